// Round 2
// baseline (744.651 us; speedup 1.0000x reference)
//
#include <hip/hip_runtime.h>
#include <math.h>

#define N_TOK 131072
#define K_CB  1024
#define D_DIM 64
// packed fixed-point units: 1/2048 of a distance unit. 72 units ~= 0.035.
#define MARGIN_U 72u

// ws layout: en[1024] f32 @0 ; es frag-major bf16 @4096 (256KB) ; fixcnt @266240 ; fixlist @266256
#define WS_EN     0
#define WS_ES     4096
#define WS_CNT    266240
#define WS_LIST   266256

typedef short bf16x8 __attribute__((ext_vector_type(8)));
typedef float f32x4  __attribute__((ext_vector_type(4)));

__device__ __forceinline__ ushort f2bf(float f) {   // RNE fp32->bf16
    uint u = __float_as_uint(f);
    u += 0x7FFFu + ((u >> 16) & 1u);
    return (ushort)(u >> 16);
}
__device__ __forceinline__ float bf2f(ushort h) {
    return __uint_as_float(((uint)h) << 16);
}

// ---- kernel 1: prep. en[k] + FRAG-MAJOR bf16 hi/lo split:
// es[(((cb*4+ks)*4+quad)*16+j)*8+e] (cb=k>>4, j=k&15): B-frag load for (cb,ks) is one
// contiguous 1KB wave load (lane = quad*16+j).
__global__ __launch_bounds__(256) void prep_kernel(
    const float* __restrict__ emb, float* __restrict__ en,
    ushort* __restrict__ es, uint* __restrict__ fixcnt)
{
    const int tid = threadIdx.x;
    const int pb  = blockIdx.x;
    const int c6  = tid & 63;
    const int q   = tid >> 6;
    const int code = pb * 64 + c6;
    if (pb == 0 && tid == 0) *fixcnt = 0;

    const int cb = code >> 4, jj = code & 15;
    const float* er = emb + (size_t)code * D_DIM;
    #pragma unroll
    for (int j = 0; j < 16; ++j) {
        int d = q * 16 + j;
        float f = er[d];
        ushort h = f2bf(f);
        ushort l = f2bf(f - bf2f(h));
        int ks = d >> 5, quad = (d >> 3) & 3, e = d & 7;
        es[(size_t)(((cb * 4 + ks)     * 4 + quad) * 16 + jj) * 8 + e] = h;
        es[(size_t)(((cb * 4 + ks + 2) * 4 + quad) * 16 + jj) * 8 + e] = l;
    }
    if (q == 0) {
        float s = 0.f;
        #pragma unroll
        for (int d = 0; d < D_DIM; ++d) s = fmaf(er[d], er[d], s);
        en[code] = s;
    }
}

// ---- kernel 2: fused argmin, K-SPLIT waves. Block = 64 rows, 4 waves: wave (rg,h)
// handles rows rg*32..+32 x chunk-half h (512 codes). The block's 256KB probs
// zero-region is written INTERLEAVED into the 32-iter MFMA loop (nontemporal, so
// the stream doesn't evict es from L2); after the LDS merge one 1.0f is scattered
// per row (same-block zero->one order guaranteed by the vmcnt drain in barrier).
// Argmin state is PACKED: u = ((uint)(2048*(en+512-2dot)) << 10) | code, so top-2
// tracking is pure u32 min/max and ties resolve to the smaller code (first-min).
__global__ __launch_bounds__(256) void vq_onehot(
    const float* __restrict__ x, const float* __restrict__ emb,
    const float* __restrict__ en, const ushort* __restrict__ es,
    float* __restrict__ zq, float* __restrict__ probs,
    uint* __restrict__ fixcnt, uint* __restrict__ fixlist, uint fixcap)
{
    const int tid  = threadIdx.x;
    const int wave = tid >> 6, lane = tid & 63;
    const int quad = lane >> 4, l15 = lane & 15;
    const int rg = wave >> 1;          // row half (32 rows)
    const int h  = wave & 1;           // chunk half (32 chunks = 512 codes)
    const int blockRow = blockIdx.x * 64;
    const int waveRowBase = blockRow + rg * 32;

    __shared__ uint lds_b1[2][64];
    __shared__ uint lds_b2[2][64];
    __shared__ int  lds_bk[64];

    // A-frags per row-group g: [0]=hi d0..31, [1]=hi d32..63, [2]=lo d0..31, [3]=lo d32..63.
    // A layout (m120): A[m=lane&15][k=quad*8+j].
    bf16x8 af[2][4];
    #pragma unroll
    for (int g = 0; g < 2; ++g) {
        const float* xr = x + (size_t)(waveRowBase + g * 16 + l15) * D_DIM + quad * 8;
        f32x4 p0 = *(const f32x4*)(xr);
        f32x4 p1 = *(const f32x4*)(xr + 4);
        f32x4 p2 = *(const f32x4*)(xr + 32);
        f32x4 p3 = *(const f32x4*)(xr + 36);
        float v0[8], v1[8];
        #pragma unroll
        for (int j = 0; j < 4; ++j) { v0[j] = p0[j]; v0[4 + j] = p1[j]; v1[j] = p2[j]; v1[4 + j] = p3[j]; }
        #pragma unroll
        for (int j = 0; j < 8; ++j) {
            ushort h0 = f2bf(v0[j]);
            af[g][0][j] = (short)h0;
            af[g][2][j] = (short)f2bf(v0[j] - bf2f(h0));
            ushort h1 = f2bf(v1[j]);
            af[g][1][j] = (short)h1;
            af[g][3][j] = (short)f2bf(v1[j] - bf2f(h1));
        }
    }

    uint b1u[8], b2u[8];
    #pragma unroll
    for (int s = 0; s < 8; ++s) { b1u[s] = 0xFFFFFFFFu; b2u[s] = 0xFFFFFFFFu; }

    const bf16x8* __restrict__ esv = (const bf16x8*)es;   // frag-major
    const int fidx = quad * 16 + l15;                     // contiguous 1KB per inst
    const int cb0  = h * 32;

    bf16x8 bc[4]; float enc;
    #pragma unroll
    for (int ks = 0; ks < 4; ++ks) bc[ks] = esv[(size_t)cb0 * 256 + ks * 64 + fidx];
    // enc = 2048*(en + 512): fixed-point bias folded in. 512 bias keeps
    // en - 2dot + 512 > 0 (>= 512 - ||x||^2, and P(||x||^2 > 512) ~ 0).
    enc = fmaf(en[cb0 * 16 + l15], 2048.f, 1048576.f);

    const f32x4 zv = {0.f, 0.f, 0.f, 0.f};
    f32x4* pz0 = (f32x4*)probs + (size_t)blockRow * 256 + (size_t)wave * 128 + lane * 2;

    #pragma unroll 2
    for (int i = 0; i < 32; ++i) {
        const int cb  = cb0 + i;
        const int nbi = cb0 + ((i + 1) & 31);
        bf16x8 bn[4]; float enn;
        #pragma unroll
        for (int ks = 0; ks < 4; ++ks) bn[ks] = esv[(size_t)nbi * 256 + ks * 64 + fidx];
        enn = fmaf(en[nbi * 16 + l15], 2048.f, 1048576.f);

        // interleaved nontemporal zero-fill of this block's probs rows:
        // 4 waves x 32 iters x 2KB = 256KB = 64 rows x 4KB.
        {
            f32x4* pz = pz0 + (size_t)i * 512;
            __builtin_nontemporal_store(zv, pz);
            __builtin_nontemporal_store(zv, pz + 1);
        }

        f32x4 acc0 = {0.f, 0.f, 0.f, 0.f};
        f32x4 acc1 = {0.f, 0.f, 0.f, 0.f};
        // dot = xh*eh + xh*el + xl*eh  (xl*el ~1e-4, absorbed by margin)
        acc0 = __builtin_amdgcn_mfma_f32_16x16x32_bf16(af[0][0], bc[0], acc0, 0, 0, 0);
        acc0 = __builtin_amdgcn_mfma_f32_16x16x32_bf16(af[0][1], bc[1], acc0, 0, 0, 0);
        acc0 = __builtin_amdgcn_mfma_f32_16x16x32_bf16(af[0][0], bc[2], acc0, 0, 0, 0);
        acc0 = __builtin_amdgcn_mfma_f32_16x16x32_bf16(af[0][1], bc[3], acc0, 0, 0, 0);
        acc0 = __builtin_amdgcn_mfma_f32_16x16x32_bf16(af[0][2], bc[0], acc0, 0, 0, 0);
        acc0 = __builtin_amdgcn_mfma_f32_16x16x32_bf16(af[0][3], bc[1], acc0, 0, 0, 0);
        acc1 = __builtin_amdgcn_mfma_f32_16x16x32_bf16(af[1][0], bc[0], acc1, 0, 0, 0);
        acc1 = __builtin_amdgcn_mfma_f32_16x16x32_bf16(af[1][1], bc[1], acc1, 0, 0, 0);
        acc1 = __builtin_amdgcn_mfma_f32_16x16x32_bf16(af[1][0], bc[2], acc1, 0, 0, 0);
        acc1 = __builtin_amdgcn_mfma_f32_16x16x32_bf16(af[1][1], bc[3], acc1, 0, 0, 0);
        acc1 = __builtin_amdgcn_mfma_f32_16x16x32_bf16(af[1][2], bc[0], acc1, 0, 0, 0);
        acc1 = __builtin_amdgcn_mfma_f32_16x16x32_bf16(af[1][3], bc[1], acc1, 0, 0, 0);

        const uint code = (uint)(cb * 16 + l15);
        // C layout (m89): col = lane&15 (this lane's code), row = quad*4 + r.
        #pragma unroll
        for (int r = 0; r < 4; ++r) {
            {
                float f = fmaf(-4096.f, acc0[r], enc);     // 2048*(en+512-2dot) >= 0
                uint u = ((uint)f << 10) | code;           // < 2^31, code in low bits
                uint lo = min(b1u[r], u), hi = max(b1u[r], u);
                b1u[r] = lo; b2u[r] = min(b2u[r], hi);
            }
            {
                int s = 4 + r;
                float f = fmaf(-4096.f, acc1[r], enc);
                uint u = ((uint)f << 10) | code;
                uint lo = min(b1u[s], u), hi = max(b1u[s], u);
                b1u[s] = lo; b2u[s] = min(b2u[s], hi);
            }
        }

        #pragma unroll
        for (int ks = 0; ks < 4; ++ks) bc[ks] = bn[ks];
        enc = enn;
    }

    // butterfly top-2 merge across the 16 lanes holding one row's columns
    #pragma unroll
    for (int s = 0; s < 8; ++s) {
        #pragma unroll
        for (int off = 1; off < 16; off <<= 1) {
            uint o1 = (uint)__shfl_xor((int)b1u[s], off);
            uint o2 = (uint)__shfl_xor((int)b2u[s], off);
            uint lo = min(b1u[s], o1), hi = max(b1u[s], o1);
            b1u[s] = lo;
            b2u[s] = min(min(b2u[s], o2), hi);
        }
    }

    // publish per-half stats
    if (l15 == 0) {
        #pragma unroll
        for (int s = 0; s < 8; ++s) {
            int idx = rg * 32 + (s >> 2) * 16 + quad * 4 + (s & 3);  // 0..63 in-block row
            lds_b1[h][idx] = b1u[s];
            lds_b2[h][idx] = b2u[s];
        }
    }
    __syncthreads();

    // merge chunk halves (code bits in the packed key give first-min tie-break);
    // scatter the single 1.0f per row (zeros from this block already drained at barrier)
    if (tid < 64) {
        uint a1 = lds_b1[0][tid], a2 = lds_b2[0][tid];
        uint c1 = lds_b1[1][tid], c2 = lds_b2[1][tid];
        uint m1 = min(a1, c1);
        uint m2 = min(min(a2, c2), max(a1, c1));
        int  mk = (int)(m1 & 1023u);
        lds_bk[tid] = mk;
        probs[(size_t)(blockRow + tid) * K_CB + mk] = 1.0f;
        if ((m2 >> 10) - (m1 >> 10) <= MARGIN_U) {
            uint idx = atomicAdd(fixcnt, 1u);
            if (idx < fixcap) fixlist[idx] = (uint)(blockRow + tid) | ((uint)mk << 17);
        }
    }
    __syncthreads();

    // zq: wave w writes rows [w*16, w*16+16): 4 rows/step, quad = row, l15 = col
    #pragma unroll
    for (int mb = 0; mb < 4; ++mb) {
        int rl = wave * 16 + mb * 4 + quad;
        int bk = lds_bk[rl];
        f32x4 v = ((const f32x4*)(emb + (size_t)bk * D_DIM))[l15];
        __builtin_nontemporal_store(v, (f32x4*)(zq + (size_t)(blockRow + rl) * D_DIM) + l15);
    }
}

// ---- kernel 3: exact fp32 re-argmin for flagged rows, coalesced: wave-per-row,
// lane = (code l15) x (d-slice quad); 16-line (not 64-line) loads + shfl reduce.
__global__ __launch_bounds__(256) void vq_fixup(
    const float* __restrict__ x, const float* __restrict__ emb,
    const float* __restrict__ en,
    float* __restrict__ zq, float* __restrict__ probs,
    const uint* __restrict__ fixcnt, const uint* __restrict__ fixlist, uint fixcap)
{
    const int lane = threadIdx.x & 63;
    const int quad = lane >> 4, l15 = lane & 15;
    const uint gwave = (uint)((blockIdx.x * 256 + threadIdx.x) >> 6);
    uint cnt = *fixcnt;
    if (cnt > fixcap) cnt = fixcap;

    for (uint e = gwave; e < cnt; e += 4096u) {
        uint w = fixlist[e];
        int row = (int)(w & 0x1FFFFu);
        int kg  = (int)(w >> 17);

        // x d-slice for this quad: d in [quad*16, quad*16+16)
        const f32x4* xr4 = (const f32x4*)(x + (size_t)row * D_DIM) + quad * 4;
        f32x4 xv[4];
        #pragma unroll
        for (int c = 0; c < 4; ++c) xv[c] = xr4[c];
        float xn = 0.f;
        #pragma unroll
        for (int c = 0; c < 4; ++c)
            #pragma unroll
            for (int j = 0; j < 4; ++j) xn = fmaf(xv[c][j], xv[c][j], xn);
        xn += __shfl_xor(xn, 16);
        xn += __shfl_xor(xn, 32);

        float bd = INFINITY; int bk = 0;
        #pragma unroll 2
        for (int t = 0; t < 64; ++t) {
            int code = t * 16 + l15;                 // ascending per lane
            const f32x4* er4 = (const f32x4*)(emb + (size_t)code * D_DIM) + quad * 4;
            float dot = 0.f;
            #pragma unroll
            for (int c = 0; c < 4; ++c) {
                f32x4 ev = er4[c];
                #pragma unroll
                for (int j = 0; j < 4; ++j) dot = fmaf(xv[c][j], ev[j], dot);
            }
            dot += __shfl_xor(dot, 16);              // sum 4 quad partials
            dot += __shfl_xor(dot, 32);
            float dist = fmaf(-2.f, dot, xn + en[code]);
            if (dist < bd) { bd = dist; bk = code; } // strict <, ascending codes
        }
        #pragma unroll
        for (int off = 1; off < 16; off <<= 1) {     // codes live across l15 group
            float od = __shfl_xor(bd, off);
            int   ok = __shfl_xor(bk, off);
            if (od < bd || (od == bd && ok < bk)) { bd = od; bk = ok; }
        }
        if (bk != kg) {
            if (lane == 0) {
                probs[(size_t)row * K_CB + kg] = 0.f;
                probs[(size_t)row * K_CB + bk] = 1.f;
            }
            if (lane < 16)
                ((f32x4*)(zq + (size_t)row * D_DIM))[lane] =
                    ((const f32x4*)(emb + (size_t)bk * D_DIM))[lane];
        }
    }
}

extern "C" void kernel_launch(void* const* d_in, const int* in_sizes, int n_in,
                              void* d_out, int out_size, void* d_ws, size_t ws_size,
                              hipStream_t stream) {
    const float* x   = (const float*)d_in[0];   // [N, D] fp32
    const float* emb = (const float*)d_in[1];   // [K, D] fp32
    float* zq    = (float*)d_out;                              // [N, D]
    float* probs = (float*)d_out + (size_t)N_TOK * D_DIM;      // [N, K]

    char* ws = (char*)d_ws;
    float*  en      = (float*)(ws + WS_EN);
    ushort* es      = (ushort*)(ws + WS_ES);
    uint*   fixcnt  = (uint*)(ws + WS_CNT);
    uint*   fixlist = (uint*)(ws + WS_LIST);
    uint fixcap = (ws_size > WS_LIST + 4) ? (uint)((ws_size - WS_LIST) / 4) : 0u;

    prep_kernel<<<16, 256, 0, stream>>>(emb, en, es, fixcnt);
    vq_onehot<<<N_TOK / 64, 256, 0, stream>>>(x, emb, en, es, zq, probs, fixcnt, fixlist, fixcap);
    vq_fixup<<<1024, 256, 0, stream>>>(x, emb, en, zq, probs, fixcnt, fixlist, fixcap);
}

// Round 3
// 648.109 us; speedup vs baseline: 1.1490x; 1.1490x over previous
//
#include <hip/hip_runtime.h>
#include <math.h>

#define N_TOK 131072
#define K_CB  1024
#define D_DIM 64
#define MARGIN 0.008f

// ws layout: en[1024] f32 @0 ; es frag-major bf16 @4096 (256KB) ; fixcnt @266240 ; fixlist @266256
#define WS_EN     0
#define WS_ES     4096
#define WS_CNT    266240
#define WS_LIST   266256

typedef short bf16x8 __attribute__((ext_vector_type(8)));
typedef float f32x4  __attribute__((ext_vector_type(4)));

__device__ __forceinline__ ushort f2bf(float f) {   // RNE fp32->bf16
    uint u = __float_as_uint(f);
    u += 0x7FFFu + ((u >> 16) & 1u);
    return (ushort)(u >> 16);
}
__device__ __forceinline__ float bf2f(ushort h) {
    return __uint_as_float(((uint)h) << 16);
}

// ---- kernel 1: prep, VECTORIZED. Thread -> one (cb,ks,quad) 16B hi frag + 16B lo
// frag: loads 32B of emb, stores 2x16B coalesced (1KB per wave per frag-plane).
// es[((cb*4+ks)*4+quad)*16+jj] (bf16x8 units), hi at ks in {0,1}, lo at ks+2.
__global__ __launch_bounds__(256) void prep_kernel(
    const float* __restrict__ emb, float* __restrict__ en,
    ushort* __restrict__ es, uint* __restrict__ fixcnt)
{
    const int tid = threadIdx.x;
    const int b   = blockIdx.x;
    if (b == 0 && tid == 0) *fixcnt = 0;

    const int half = tid >> 7;          // which cb of this block's pair
    const int t    = tid & 127;
    const int cb   = b * 2 + half;
    const int jj   = t & 15;
    const int quad = (t >> 4) & 3;
    const int ks   = (t >> 6) & 1;
    const int code = cb * 16 + jj;

    const float* er = emb + (size_t)code * D_DIM + ks * 32 + quad * 8;
    f32x4 pa = *(const f32x4*)(er);
    f32x4 pb = *(const f32x4*)(er + 4);

    bf16x8 hi, lo;
    #pragma unroll
    for (int j = 0; j < 8; ++j) {
        float f = (j < 4) ? pa[j] : pb[j - 4];
        ushort h = f2bf(f);
        hi[j] = (short)h;
        lo[j] = (short)f2bf(f - bf2f(h));
    }
    bf16x8* out = (bf16x8*)es;
    out[(size_t)(cb * 4 + ks)     * 64 + quad * 16 + jj] = hi;
    out[(size_t)(cb * 4 + ks + 2) * 64 + quad * 16 + jj] = lo;

    if (tid < 32) {
        const int c2 = b * 32 + tid;
        const float* e2 = emb + (size_t)c2 * D_DIM;
        float s = 0.f;
        #pragma unroll
        for (int d = 0; d < D_DIM; ++d) s = fmaf(e2[d], e2[d], s);
        en[c2] = s;
    }
}

// ---- kernel 2: fused, K-SPLIT waves. Block = 64 rows, 4 waves: wave (rg,h) handles
// rows rg*32..+32 x chunk-half h (512 codes). Top-2 merged across halves in LDS,
// then fused zq + zero blast (phase-separated: no stores inside the MFMA loop,
// keeping vmcnt waits clean) + barrier + one 1.0f scatter per row.
__global__ __launch_bounds__(256) void vq_onehot(
    const float* __restrict__ x, const float* __restrict__ emb,
    const float* __restrict__ en, const ushort* __restrict__ es,
    float* __restrict__ zq, float* __restrict__ probs,
    uint* __restrict__ fixcnt, uint* __restrict__ fixlist, uint fixcap)
{
    const int tid  = threadIdx.x;
    const int wave = tid >> 6, lane = tid & 63;
    const int quad = lane >> 4, l15 = lane & 15;
    const int rg = wave >> 1;          // row half (32 rows)
    const int h  = wave & 1;           // chunk half (32 chunks = 512 codes)
    const int blockRow = blockIdx.x * 64;
    const int waveRowBase = blockRow + rg * 32;

    __shared__ float lds_b1[2][64];
    __shared__ float lds_b2[2][64];
    __shared__ int   lds_k1[2][64];
    __shared__ int   lds_bk[64];

    // A-frags per row-group g: [0]=hi d0..31, [1]=hi d32..63, [2]=lo d0..31, [3]=lo d32..63.
    // A layout (m120): A[m=lane&15][k=quad*8+j].
    bf16x8 af[2][4];
    #pragma unroll
    for (int g = 0; g < 2; ++g) {
        const float* xr = x + (size_t)(waveRowBase + g * 16 + l15) * D_DIM + quad * 8;
        f32x4 p0 = *(const f32x4*)(xr);
        f32x4 p1 = *(const f32x4*)(xr + 4);
        f32x4 p2 = *(const f32x4*)(xr + 32);
        f32x4 p3 = *(const f32x4*)(xr + 36);
        float v0[8], v1[8];
        #pragma unroll
        for (int j = 0; j < 4; ++j) { v0[j] = p0[j]; v0[4 + j] = p1[j]; v1[j] = p2[j]; v1[4 + j] = p3[j]; }
        #pragma unroll
        for (int j = 0; j < 8; ++j) {
            ushort h0 = f2bf(v0[j]);
            af[g][0][j] = (short)h0;
            af[g][2][j] = (short)f2bf(v0[j] - bf2f(h0));
            ushort h1 = f2bf(v1[j]);
            af[g][1][j] = (short)h1;
            af[g][3][j] = (short)f2bf(v1[j] - bf2f(h1));
        }
    }

    float b1[8], b2[8]; int k1[8];
    #pragma unroll
    for (int s = 0; s < 8; ++s) { b1[s] = INFINITY; b2[s] = INFINITY; k1[s] = 0; }

    const bf16x8* __restrict__ esv = (const bf16x8*)es;   // frag-major
    const int fidx = quad * 16 + l15;                     // contiguous 1KB per inst
    const int cb0  = h * 32;

    bf16x8 bc[4]; float enc;
    #pragma unroll
    for (int ks = 0; ks < 4; ++ks) bc[ks] = esv[(size_t)cb0 * 256 + ks * 64 + fidx];
    enc = en[cb0 * 16 + l15];

    #pragma unroll 2
    for (int i = 0; i < 32; ++i) {
        const int cb  = cb0 + i;
        const int nbi = cb0 + ((i + 1) & 31);
        bf16x8 bn[4]; float enn;
        #pragma unroll
        for (int ks = 0; ks < 4; ++ks) bn[ks] = esv[(size_t)nbi * 256 + ks * 64 + fidx];
        enn = en[nbi * 16 + l15];

        f32x4 acc0 = {0.f, 0.f, 0.f, 0.f};
        f32x4 acc1 = {0.f, 0.f, 0.f, 0.f};
        // dot = xh*eh + xh*el + xl*eh  (xl*el ~1e-4, absorbed by MARGIN)
        acc0 = __builtin_amdgcn_mfma_f32_16x16x32_bf16(af[0][0], bc[0], acc0, 0, 0, 0);
        acc0 = __builtin_amdgcn_mfma_f32_16x16x32_bf16(af[0][1], bc[1], acc0, 0, 0, 0);
        acc0 = __builtin_amdgcn_mfma_f32_16x16x32_bf16(af[0][0], bc[2], acc0, 0, 0, 0);
        acc0 = __builtin_amdgcn_mfma_f32_16x16x32_bf16(af[0][1], bc[3], acc0, 0, 0, 0);
        acc0 = __builtin_amdgcn_mfma_f32_16x16x32_bf16(af[0][2], bc[0], acc0, 0, 0, 0);
        acc0 = __builtin_amdgcn_mfma_f32_16x16x32_bf16(af[0][3], bc[1], acc0, 0, 0, 0);
        acc1 = __builtin_amdgcn_mfma_f32_16x16x32_bf16(af[1][0], bc[0], acc1, 0, 0, 0);
        acc1 = __builtin_amdgcn_mfma_f32_16x16x32_bf16(af[1][1], bc[1], acc1, 0, 0, 0);
        acc1 = __builtin_amdgcn_mfma_f32_16x16x32_bf16(af[1][0], bc[2], acc1, 0, 0, 0);
        acc1 = __builtin_amdgcn_mfma_f32_16x16x32_bf16(af[1][1], bc[3], acc1, 0, 0, 0);
        acc1 = __builtin_amdgcn_mfma_f32_16x16x32_bf16(af[1][2], bc[0], acc1, 0, 0, 0);
        acc1 = __builtin_amdgcn_mfma_f32_16x16x32_bf16(af[1][3], bc[1], acc1, 0, 0, 0);

        const int code = cb * 16 + l15;
        // C layout (m89): col = lane&15 (this lane's code), row = quad*4 + r.
        #pragma unroll
        for (int r = 0; r < 4; ++r) {
            {
                float d = fmaf(-2.f, acc0[r], enc);
                bool lt = d < b1[r];
                b2[r] = lt ? b1[r] : fminf(b2[r], d);
                k1[r] = lt ? code : k1[r];
                b1[r] = lt ? d : b1[r];
            }
            {
                int s = 4 + r;
                float d = fmaf(-2.f, acc1[r], enc);
                bool lt = d < b1[s];
                b2[s] = lt ? b1[s] : fminf(b2[s], d);
                k1[s] = lt ? code : k1[s];
                b1[s] = lt ? d : b1[s];
            }
        }

        #pragma unroll
        for (int ks = 0; ks < 4; ++ks) bc[ks] = bn[ks];
        enc = enn;
    }

    // butterfly top-2 merge across the 16 lanes holding one row's columns
    #pragma unroll
    for (int s = 0; s < 8; ++s) {
        #pragma unroll
        for (int off = 1; off < 16; off <<= 1) {
            float ob1 = __shfl_xor(b1[s], off);
            int   ok1 = __shfl_xor(k1[s], off);
            float ob2 = __shfl_xor(b2[s], off);
            bool better = (ob1 < b1[s]) || (ob1 == b1[s] && ok1 < k1[s]);
            float loser = better ? b1[s] : ob1;
            b1[s] = better ? ob1 : b1[s];
            k1[s] = better ? ok1 : k1[s];
            b2[s] = fminf(fminf(b2[s], ob2), loser);
        }
    }

    // publish per-half stats
    if (l15 == 0) {
        #pragma unroll
        for (int s = 0; s < 8; ++s) {
            int idx = rg * 32 + (s >> 2) * 16 + quad * 4 + (s & 3);  // 0..63 in-block row
            lds_b1[h][idx] = b1[s];
            lds_b2[h][idx] = b2[s];
            lds_k1[h][idx] = k1[s];
        }
    }
    __syncthreads();

    // merge chunk halves (half-0 codes all smaller -> wins ties = first-min)
    if (tid < 64) {
        float a1 = lds_b1[0][tid], a2 = lds_b2[0][tid]; int ak = lds_k1[0][tid];
        float c1 = lds_b1[1][tid], c2 = lds_b2[1][tid]; int ck = lds_k1[1][tid];
        bool bwin = c1 < a1;
        float m1 = bwin ? c1 : a1;
        int   mk = bwin ? ck : ak;
        float loser = bwin ? a1 : c1;
        float m2 = fminf(fminf(a2, c2), loser);
        lds_bk[tid] = mk;
        if (m2 - m1 <= MARGIN) {
            uint idx = atomicAdd(fixcnt, 1u);
            if (idx < fixcap) fixlist[idx] = (uint)(blockRow + tid) | ((uint)mk << 17);
        }
    }
    __syncthreads();

    // zq: wave w writes rows [w*16, w*16+16): 4 rows/step, quad = row, l15 = col
    #pragma unroll
    for (int mb = 0; mb < 4; ++mb) {
        int rl = wave * 16 + mb * 4 + quad;
        int bk = lds_bk[rl];
        f32x4 v = ((const f32x4*)(emb + (size_t)bk * D_DIM))[l15];
        ((f32x4*)(zq + (size_t)(blockRow + rl) * D_DIM))[l15] = v;
    }

    // zero blast: wave w streams its 16 rows x 4KB, unconditional coalesced stores
    const f32x4 zv = {0.f, 0.f, 0.f, 0.f};
    for (int m = 0; m < 16; ++m) {
        int rl = wave * 16 + m;
        float* prow = probs + (size_t)(blockRow + rl) * K_CB;
        #pragma unroll
        for (int s = 0; s < 4; ++s)
            *(f32x4*)(prow + s * 256 + lane * 4) = zv;
    }
    __syncthreads();   // drain zeros (vmcnt) before the same-address 1.0 scatter

    if (tid < 64)
        probs[(size_t)(blockRow + tid) * K_CB + lds_bk[tid]] = 1.0f;
}

// ---- kernel 3: exact fp32 re-argmin for flagged rows, coalesced: wave-per-row,
// lane = (code l15) x (d-slice quad); 16-line (not 64-line) loads + shfl reduce.
__global__ __launch_bounds__(256) void vq_fixup(
    const float* __restrict__ x, const float* __restrict__ emb,
    const float* __restrict__ en,
    float* __restrict__ zq, float* __restrict__ probs,
    const uint* __restrict__ fixcnt, const uint* __restrict__ fixlist, uint fixcap)
{
    const int lane = threadIdx.x & 63;
    const int quad = lane >> 4, l15 = lane & 15;
    const uint gwave = (uint)((blockIdx.x * 256 + threadIdx.x) >> 6);
    uint cnt = *fixcnt;
    if (cnt > fixcap) cnt = fixcap;

    for (uint e = gwave; e < cnt; e += 1024u) {
        uint w = fixlist[e];
        int row = (int)(w & 0x1FFFFu);
        int kg  = (int)(w >> 17);

        // x d-slice for this quad: d in [quad*16, quad*16+16)
        const f32x4* xr4 = (const f32x4*)(x + (size_t)row * D_DIM) + quad * 4;
        f32x4 xv[4];
        #pragma unroll
        for (int c = 0; c < 4; ++c) xv[c] = xr4[c];
        float xn = 0.f;
        #pragma unroll
        for (int c = 0; c < 4; ++c)
            #pragma unroll
            for (int j = 0; j < 4; ++j) xn = fmaf(xv[c][j], xv[c][j], xn);
        xn += __shfl_xor(xn, 16);
        xn += __shfl_xor(xn, 32);

        float bd = INFINITY; int bk = 0;
        for (int t = 0; t < 64; ++t) {
            int code = t * 16 + l15;                 // ascending per lane
            const f32x4* er4 = (const f32x4*)(emb + (size_t)code * D_DIM) + quad * 4;
            float dot = 0.f;
            #pragma unroll
            for (int c = 0; c < 4; ++c) {
                f32x4 ev = er4[c];
                #pragma unroll
                for (int j = 0; j < 4; ++j) dot = fmaf(xv[c][j], ev[j], dot);
            }
            dot += __shfl_xor(dot, 16);              // sum 4 quad partials
            dot += __shfl_xor(dot, 32);
            float dist = fmaf(-2.f, dot, xn + en[code]);
            if (dist < bd) { bd = dist; bk = code; } // strict <, ascending codes
        }
        #pragma unroll
        for (int off = 1; off < 16; off <<= 1) {     // codes live across l15 group
            float od = __shfl_xor(bd, off);
            int   ok = __shfl_xor(bk, off);
            if (od < bd || (od == bd && ok < bk)) { bd = od; bk = ok; }
        }
        if (bk != kg) {
            if (lane == 0) {
                probs[(size_t)row * K_CB + kg] = 0.f;
                probs[(size_t)row * K_CB + bk] = 1.f;
            }
            if (lane < 16)
                ((f32x4*)(zq + (size_t)row * D_DIM))[lane] =
                    ((const f32x4*)(emb + (size_t)bk * D_DIM))[lane];
        }
    }
}

extern "C" void kernel_launch(void* const* d_in, const int* in_sizes, int n_in,
                              void* d_out, int out_size, void* d_ws, size_t ws_size,
                              hipStream_t stream) {
    const float* x   = (const float*)d_in[0];   // [N, D] fp32
    const float* emb = (const float*)d_in[1];   // [K, D] fp32
    float* zq    = (float*)d_out;                              // [N, D]
    float* probs = (float*)d_out + (size_t)N_TOK * D_DIM;      // [N, K]

    char* ws = (char*)d_ws;
    float*  en      = (float*)(ws + WS_EN);
    ushort* es      = (ushort*)(ws + WS_ES);
    uint*   fixcnt  = (uint*)(ws + WS_CNT);
    uint*   fixlist = (uint*)(ws + WS_LIST);
    uint fixcap = (ws_size > WS_LIST + 4) ? (uint)((ws_size - WS_LIST) / 4) : 0u;

    prep_kernel<<<32, 256, 0, stream>>>(emb, en, es, fixcnt);
    vq_onehot<<<N_TOK / 64, 256, 0, stream>>>(x, emb, en, es, zq, probs, fixcnt, fixlist, fixcap);
    vq_fixup<<<256, 256, 0, stream>>>(x, emb, en, zq, probs, fixcnt, fixlist, fixcap);
}

// Round 4
// 644.808 us; speedup vs baseline: 1.1548x; 1.0051x over previous
//
#include <hip/hip_runtime.h>
#include <math.h>

#define N_TOK 131072
#define K_CB  1024
#define D_DIM 64
#define MARGIN 0.008f

// ws layout: en[1024] f32 @0 ; es frag-major bf16 @4096 (256KB) ; fixcnt @266240 ; fixlist @266256
#define WS_EN     0
#define WS_ES     4096
#define WS_CNT    266240
#define WS_LIST   266256

typedef short bf16x8 __attribute__((ext_vector_type(8)));
typedef float f32x4  __attribute__((ext_vector_type(4)));

__device__ __forceinline__ ushort f2bf(float f) {   // RNE fp32->bf16
    uint u = __float_as_uint(f);
    u += 0x7FFFu + ((u >> 16) & 1u);
    return (ushort)(u >> 16);
}
__device__ __forceinline__ float bf2f(ushort h) {
    return __uint_as_float(((uint)h) << 16);
}

// ---- kernel 1: prep, VECTORIZED. Thread -> one (cb,ks,quad) 16B hi frag + 16B lo
// frag: loads 32B of emb, stores 2x16B coalesced (1KB per wave per frag-plane).
// es[((cb*4+ks)*4+quad)*16+jj] (bf16x8 units), hi at ks in {0,1}, lo at ks+2.
__global__ __launch_bounds__(256) void prep_kernel(
    const float* __restrict__ emb, float* __restrict__ en,
    ushort* __restrict__ es, uint* __restrict__ fixcnt)
{
    const int tid = threadIdx.x;
    const int b   = blockIdx.x;
    if (b == 0 && tid == 0) *fixcnt = 0;

    const int half = tid >> 7;          // which cb of this block's pair
    const int t    = tid & 127;
    const int cb   = b * 2 + half;
    const int jj   = t & 15;
    const int quad = (t >> 4) & 3;
    const int ks   = (t >> 6) & 1;
    const int code = cb * 16 + jj;

    const float* er = emb + (size_t)code * D_DIM + ks * 32 + quad * 8;
    f32x4 pa = *(const f32x4*)(er);
    f32x4 pb = *(const f32x4*)(er + 4);

    bf16x8 hi, lo;
    #pragma unroll
    for (int j = 0; j < 8; ++j) {
        float f = (j < 4) ? pa[j] : pb[j - 4];
        ushort h = f2bf(f);
        hi[j] = (short)h;
        lo[j] = (short)f2bf(f - bf2f(h));
    }
    bf16x8* out = (bf16x8*)es;
    out[(size_t)(cb * 4 + ks)     * 64 + quad * 16 + jj] = hi;
    out[(size_t)(cb * 4 + ks + 2) * 64 + quad * 16 + jj] = lo;

    if (tid < 32) {
        const int c2 = b * 32 + tid;
        const float* e2 = emb + (size_t)c2 * D_DIM;
        float s = 0.f;
        #pragma unroll
        for (int d = 0; d < D_DIM; ++d) s = fmaf(e2[d], e2[d], s);
        en[c2] = s;
    }
}

// ---- kernel 2: fused, K-SPLIT waves. Block = 64 rows, 4 waves: wave (rg,h) handles
// rows rg*32..+32 x chunk-half h (512 codes). ITERATION ORDER IS ROTATED by a
// per-block offset ((blockIdx>>3)&31, so same-XCD neighbors differ): all 2048
// blocks read the same 256KB es, and in lockstep identical order every CU hits the
// same L2 slice simultaneously (slice-port serialization). Rotation decorrelates.
// Min-tracking is order-independent; exact ties are margin-flagged and re-resolved
// exactly by vq_fixup, so the visit order cannot change results.
__global__ __launch_bounds__(256) void vq_onehot(
    const float* __restrict__ x, const float* __restrict__ emb,
    const float* __restrict__ en, const ushort* __restrict__ es,
    float* __restrict__ zq, float* __restrict__ probs,
    uint* __restrict__ fixcnt, uint* __restrict__ fixlist, uint fixcap)
{
    const int tid  = threadIdx.x;
    const int wave = tid >> 6, lane = tid & 63;
    const int quad = lane >> 4, l15 = lane & 15;
    const int rg = wave >> 1;          // row half (32 rows)
    const int h  = wave & 1;           // chunk half (32 chunks = 512 codes)
    const int blockRow = blockIdx.x * 64;
    const int waveRowBase = blockRow + rg * 32;
    const int boff = (blockIdx.x >> 3) & 31;   // L2-slice decorrelation

    __shared__ float lds_b1[2][64];
    __shared__ float lds_b2[2][64];
    __shared__ int   lds_k1[2][64];
    __shared__ int   lds_bk[64];

    // A-frags per row-group g: [0]=hi d0..31, [1]=hi d32..63, [2]=lo d0..31, [3]=lo d32..63.
    // A layout (m120): A[m=lane&15][k=quad*8+j].
    bf16x8 af[2][4];
    #pragma unroll
    for (int g = 0; g < 2; ++g) {
        const float* xr = x + (size_t)(waveRowBase + g * 16 + l15) * D_DIM + quad * 8;
        f32x4 p0 = *(const f32x4*)(xr);
        f32x4 p1 = *(const f32x4*)(xr + 4);
        f32x4 p2 = *(const f32x4*)(xr + 32);
        f32x4 p3 = *(const f32x4*)(xr + 36);
        float v0[8], v1[8];
        #pragma unroll
        for (int j = 0; j < 4; ++j) { v0[j] = p0[j]; v0[4 + j] = p1[j]; v1[j] = p2[j]; v1[4 + j] = p3[j]; }
        #pragma unroll
        for (int j = 0; j < 8; ++j) {
            ushort h0 = f2bf(v0[j]);
            af[g][0][j] = (short)h0;
            af[g][2][j] = (short)f2bf(v0[j] - bf2f(h0));
            ushort h1 = f2bf(v1[j]);
            af[g][1][j] = (short)h1;
            af[g][3][j] = (short)f2bf(v1[j] - bf2f(h1));
        }
    }

    float b1[8], b2[8]; int k1[8];
    #pragma unroll
    for (int s = 0; s < 8; ++s) { b1[s] = INFINITY; b2[s] = INFINITY; k1[s] = 0; }

    const bf16x8* __restrict__ esv = (const bf16x8*)es;   // frag-major
    const int fidx = quad * 16 + l15;                     // contiguous 1KB per inst
    const int cb0  = h * 32;

    bf16x8 bc[4]; float enc;
    {
        const int cbs = cb0 + boff;
        #pragma unroll
        for (int ks = 0; ks < 4; ++ks) bc[ks] = esv[(size_t)cbs * 256 + ks * 64 + fidx];
        enc = en[cbs * 16 + l15];
    }

    #pragma unroll 2
    for (int i = 0; i < 32; ++i) {
        const int cb  = cb0 + ((i + boff) & 31);
        const int nbi = cb0 + ((i + 1 + boff) & 31);
        bf16x8 bn[4]; float enn;
        #pragma unroll
        for (int ks = 0; ks < 4; ++ks) bn[ks] = esv[(size_t)nbi * 256 + ks * 64 + fidx];
        enn = en[nbi * 16 + l15];

        f32x4 acc0 = {0.f, 0.f, 0.f, 0.f};
        f32x4 acc1 = {0.f, 0.f, 0.f, 0.f};
        // dot = xh*eh + xh*el + xl*eh  (xl*el ~1e-4, absorbed by MARGIN)
        acc0 = __builtin_amdgcn_mfma_f32_16x16x32_bf16(af[0][0], bc[0], acc0, 0, 0, 0);
        acc0 = __builtin_amdgcn_mfma_f32_16x16x32_bf16(af[0][1], bc[1], acc0, 0, 0, 0);
        acc0 = __builtin_amdgcn_mfma_f32_16x16x32_bf16(af[0][0], bc[2], acc0, 0, 0, 0);
        acc0 = __builtin_amdgcn_mfma_f32_16x16x32_bf16(af[0][1], bc[3], acc0, 0, 0, 0);
        acc0 = __builtin_amdgcn_mfma_f32_16x16x32_bf16(af[0][2], bc[0], acc0, 0, 0, 0);
        acc0 = __builtin_amdgcn_mfma_f32_16x16x32_bf16(af[0][3], bc[1], acc0, 0, 0, 0);
        acc1 = __builtin_amdgcn_mfma_f32_16x16x32_bf16(af[1][0], bc[0], acc1, 0, 0, 0);
        acc1 = __builtin_amdgcn_mfma_f32_16x16x32_bf16(af[1][1], bc[1], acc1, 0, 0, 0);
        acc1 = __builtin_amdgcn_mfma_f32_16x16x32_bf16(af[1][0], bc[2], acc1, 0, 0, 0);
        acc1 = __builtin_amdgcn_mfma_f32_16x16x32_bf16(af[1][1], bc[3], acc1, 0, 0, 0);
        acc1 = __builtin_amdgcn_mfma_f32_16x16x32_bf16(af[1][2], bc[0], acc1, 0, 0, 0);
        acc1 = __builtin_amdgcn_mfma_f32_16x16x32_bf16(af[1][3], bc[1], acc1, 0, 0, 0);

        const int code = cb * 16 + l15;
        // C layout (m89): col = lane&15 (this lane's code), row = quad*4 + r.
        #pragma unroll
        for (int r = 0; r < 4; ++r) {
            {
                float d = fmaf(-2.f, acc0[r], enc);
                bool lt = d < b1[r];
                b2[r] = lt ? b1[r] : fminf(b2[r], d);
                k1[r] = lt ? code : k1[r];
                b1[r] = lt ? d : b1[r];
            }
            {
                int s = 4 + r;
                float d = fmaf(-2.f, acc1[r], enc);
                bool lt = d < b1[s];
                b2[s] = lt ? b1[s] : fminf(b2[s], d);
                k1[s] = lt ? code : k1[s];
                b1[s] = lt ? d : b1[s];
            }
        }

        #pragma unroll
        for (int ks = 0; ks < 4; ++ks) bc[ks] = bn[ks];
        enc = enn;
    }

    // butterfly top-2 merge across the 16 lanes holding one row's columns
    #pragma unroll
    for (int s = 0; s < 8; ++s) {
        #pragma unroll
        for (int off = 1; off < 16; off <<= 1) {
            float ob1 = __shfl_xor(b1[s], off);
            int   ok1 = __shfl_xor(k1[s], off);
            float ob2 = __shfl_xor(b2[s], off);
            bool better = (ob1 < b1[s]) || (ob1 == b1[s] && ok1 < k1[s]);
            float loser = better ? b1[s] : ob1;
            b1[s] = better ? ob1 : b1[s];
            k1[s] = better ? ok1 : k1[s];
            b2[s] = fminf(fminf(b2[s], ob2), loser);
        }
    }

    // publish per-half stats
    if (l15 == 0) {
        #pragma unroll
        for (int s = 0; s < 8; ++s) {
            int idx = rg * 32 + (s >> 2) * 16 + quad * 4 + (s & 3);  // 0..63 in-block row
            lds_b1[h][idx] = b1[s];
            lds_b2[h][idx] = b2[s];
            lds_k1[h][idx] = k1[s];
        }
    }
    __syncthreads();

    // merge chunk halves. Within-lane ties across the rotated order are arbitrary,
    // but any tie has gap 0 <= MARGIN -> flagged -> fixup resolves exactly.
    if (tid < 64) {
        float a1 = lds_b1[0][tid], a2 = lds_b2[0][tid]; int ak = lds_k1[0][tid];
        float c1 = lds_b1[1][tid], c2 = lds_b2[1][tid]; int ck = lds_k1[1][tid];
        bool bwin = c1 < a1;
        float m1 = bwin ? c1 : a1;
        int   mk = bwin ? ck : ak;
        float loser = bwin ? a1 : c1;
        float m2 = fminf(fminf(a2, c2), loser);
        lds_bk[tid] = mk;
        if (m2 - m1 <= MARGIN) {
            uint idx = atomicAdd(fixcnt, 1u);
            if (idx < fixcap) fixlist[idx] = (uint)(blockRow + tid) | ((uint)mk << 17);
        }
    }
    __syncthreads();

    // zq: wave w writes rows [w*16, w*16+16): 4 rows/step, quad = row, l15 = col
    #pragma unroll
    for (int mb = 0; mb < 4; ++mb) {
        int rl = wave * 16 + mb * 4 + quad;
        int bk = lds_bk[rl];
        f32x4 v = ((const f32x4*)(emb + (size_t)bk * D_DIM))[l15];
        ((f32x4*)(zq + (size_t)(blockRow + rl) * D_DIM))[l15] = v;
    }

    // zero blast: wave w streams its 16 rows x 4KB, unconditional coalesced stores
    const f32x4 zv = {0.f, 0.f, 0.f, 0.f};
    for (int m = 0; m < 16; ++m) {
        int rl = wave * 16 + m;
        float* prow = probs + (size_t)(blockRow + rl) * K_CB;
        #pragma unroll
        for (int s = 0; s < 4; ++s)
            *(f32x4*)(prow + s * 256 + lane * 4) = zv;
    }
    __syncthreads();   // drain zeros (vmcnt) before the same-address 1.0 scatter

    if (tid < 64)
        probs[(size_t)(blockRow + tid) * K_CB + lds_bk[tid]] = 1.0f;
}

// ---- kernel 3: exact fp32 re-argmin for flagged rows, coalesced: wave-per-row,
// lane = (code l15) x (d-slice quad); 16-line (not 64-line) loads + shfl reduce.
__global__ __launch_bounds__(256) void vq_fixup(
    const float* __restrict__ x, const float* __restrict__ emb,
    const float* __restrict__ en,
    float* __restrict__ zq, float* __restrict__ probs,
    const uint* __restrict__ fixcnt, const uint* __restrict__ fixlist, uint fixcap)
{
    const int lane = threadIdx.x & 63;
    const int quad = lane >> 4, l15 = lane & 15;
    const uint gwave = (uint)((blockIdx.x * 256 + threadIdx.x) >> 6);
    uint cnt = *fixcnt;
    if (cnt > fixcap) cnt = fixcap;

    for (uint e = gwave; e < cnt; e += 1024u) {
        uint w = fixlist[e];
        int row = (int)(w & 0x1FFFFu);
        int kg  = (int)(w >> 17);

        // x d-slice for this quad: d in [quad*16, quad*16+16)
        const f32x4* xr4 = (const f32x4*)(x + (size_t)row * D_DIM) + quad * 4;
        f32x4 xv[4];
        #pragma unroll
        for (int c = 0; c < 4; ++c) xv[c] = xr4[c];
        float xn = 0.f;
        #pragma unroll
        for (int c = 0; c < 4; ++c)
            #pragma unroll
            for (int j = 0; j < 4; ++j) xn = fmaf(xv[c][j], xv[c][j], xn);
        xn += __shfl_xor(xn, 16);
        xn += __shfl_xor(xn, 32);

        float bd = INFINITY; int bk = 0;
        for (int t = 0; t < 64; ++t) {
            int code = t * 16 + l15;                 // ascending per lane
            const f32x4* er4 = (const f32x4*)(emb + (size_t)code * D_DIM) + quad * 4;
            float dot = 0.f;
            #pragma unroll
            for (int c = 0; c < 4; ++c) {
                f32x4 ev = er4[c];
                #pragma unroll
                for (int j = 0; j < 4; ++j) dot = fmaf(xv[c][j], ev[j], dot);
            }
            dot += __shfl_xor(dot, 16);              // sum 4 quad partials
            dot += __shfl_xor(dot, 32);
            float dist = fmaf(-2.f, dot, xn + en[code]);
            if (dist < bd) { bd = dist; bk = code; } // strict <, ascending codes
        }
        #pragma unroll
        for (int off = 1; off < 16; off <<= 1) {     // codes live across l15 group
            float od = __shfl_xor(bd, off);
            int   ok = __shfl_xor(bk, off);
            if (od < bd || (od == bd && ok < bk)) { bd = od; bk = ok; }
        }
        if (bk != kg) {
            if (lane == 0) {
                probs[(size_t)row * K_CB + kg] = 0.f;
                probs[(size_t)row * K_CB + bk] = 1.f;
            }
            if (lane < 16)
                ((f32x4*)(zq + (size_t)row * D_DIM))[lane] =
                    ((const f32x4*)(emb + (size_t)bk * D_DIM))[lane];
        }
    }
}

extern "C" void kernel_launch(void* const* d_in, const int* in_sizes, int n_in,
                              void* d_out, int out_size, void* d_ws, size_t ws_size,
                              hipStream_t stream) {
    const float* x   = (const float*)d_in[0];   // [N, D] fp32
    const float* emb = (const float*)d_in[1];   // [K, D] fp32
    float* zq    = (float*)d_out;                              // [N, D]
    float* probs = (float*)d_out + (size_t)N_TOK * D_DIM;      // [N, K]

    char* ws = (char*)d_ws;
    float*  en      = (float*)(ws + WS_EN);
    ushort* es      = (ushort*)(ws + WS_ES);
    uint*   fixcnt  = (uint*)(ws + WS_CNT);
    uint*   fixlist = (uint*)(ws + WS_LIST);
    uint fixcap = (ws_size > WS_LIST + 4) ? (uint)((ws_size - WS_LIST) / 4) : 0u;

    prep_kernel<<<32, 256, 0, stream>>>(emb, en, es, fixcnt);
    vq_onehot<<<N_TOK / 64, 256, 0, stream>>>(x, emb, en, es, zq, probs, fixcnt, fixlist, fixcap);
    vq_fixup<<<256, 256, 0, stream>>>(x, emb, en, zq, probs, fixcnt, fixlist, fixcap);
}